// Round 9
// baseline (528.330 us; speedup 1.0000x reference)
//
#include <hip/hip_runtime.h>
#include <hip/hip_bf16.h>

typedef _Float16 f16x8 __attribute__((ext_vector_type(8)));
typedef _Float16 f16x4 __attribute__((ext_vector_type(4)));
typedef float    f32x4 __attribute__((ext_vector_type(4)));

#define HW   36864   // 192*192
#define W_   192
#define NS   9216    // 96*96 patches
#define CCH  128     // channels (QK inner dim)
#define DV   512     // c*r*r  (PV output dim)
#define ROWS 64      // query rows per block
#define KV   64      // keys per tile
#define NT   144     // total key tiles
#define LOG2E 1.44269504089f
#define LN2   0.69314718056f
#define THR2  11.5417f        // defer-max threshold (=8 nats) in log2 domain

#define EXP2(x) __builtin_exp2f(x)

// ---------- prep: Vt[d][m] (f16, transposed patches) + F16[m][c] (f16 feat) ----------
__global__ __launch_bounds__(256) void prep_vt_kernel(const float* __restrict__ x,
        _Float16* __restrict__ Vt, _Float16* __restrict__ F16)
{
    int m = blockIdx.x * 256 + threadIdx.x;   // 0..9215
    int d = blockIdx.y;                       // 0..511
    int c = d >> 2, di = (d >> 1) & 1, dj = d & 1;
    int i = m / 96, j = m - i * 96;
    float v = x[c * HW + (2 * i + di) * W_ + (2 * j + dj)];
    _Float16 h = (_Float16)v;
    Vt[(size_t)d * NS + m] = h;
    if ((d & 3) == 0) F16[m * CCH + c] = h;   // di=dj=0 element == feat
}

// ---------- prep: csv[m] = scale (log2 domain), csb[m] = additive mask bias ----------
__global__ __launch_bounds__(64) void prep_csv_kernel(const _Float16* __restrict__ F16,
        const float* __restrict__ mask, float* __restrict__ csv, float* __restrict__ csb)
{
    int m = blockIdx.x;
    int t = threadIdx.x;                      // one wave
    float a = (float)F16[m * CCH + 2 * t];
    float b = (float)F16[m * CCH + 2 * t + 1];
    float ss = a * a + b * b;
    #pragma unroll
    for (int off = 1; off <= 32; off <<= 1)
        ss += __shfl_xor(ss, off);
    if (t == 0) {
        int i = m / 96, j = m - i * 96;
        float ms = mask[(2 * i) * W_ + 2 * j];
        bool valid = (ms == 0.0f);
        csv[m] = valid ? 10.0f * LOG2E / (sqrtf(ss) + 1e-8f) : 0.0f;
        csb[m] = valid ? 0.0f : -60000.0f;    // exp2(-60000 - m2) == 0 for m2 >= -20000
    }
}

// ---------- fused masked attention: 64 rows x 256 d, 4 waves, 1 barrier/tile ----------
// Wave wv: QK role = rowgroup wv (16 queries x 64 keys, swapped mfma(K,Q), softmax fully
// in-wave, log2 domain), PV role = d-slice wv*64 (all 64 rows). K double-buffered via
// global_load_lds staged at TILE TOP (latency hides under V-prefetch+QK+softmax).
template<int KT>
__global__ __launch_bounds__(256, 3) void flash_kernel(const _Float16* __restrict__ F16,
        const _Float16* __restrict__ Vt, const float* __restrict__ csv,
        const float* __restrict__ csb, _Float16* __restrict__ po, float* __restrict__ av)
{
    constexpr int SPLT = NT / KT;
    __shared__ __align__(16) _Float16 Kb[2][KV * CCH];   // 2 x 16 KB, [key][chunk^(key&7)]
    __shared__ __align__(16) _Float16 Pb[2][ROWS * KV];  // 2 x 8 KB,  [row][chunk^(row&7)]
    __shared__ __align__(16) float    abuf[2][ROWS];     // per-row rescale factors
    __shared__ __align__(16) int      flags[2][4];       // per-wave rescale flags
    __shared__ __align__(16) float    lbuf[ROWS];        // final 1/l

    const int tid  = threadIdx.x;
    const int wv   = tid >> 6;
    const int lane = tid & 63;
    const int g    = lane >> 4, c16 = lane & 15;
    const int flat = blockIdx.x;
    const int sp   = flat % SPLT;      // same split -> same XCD (round-robin dispatch)
    const int rest = flat / SPLT;
    const int n0   = (rest >> 1) * ROWS;
    const int d0   = (rest & 1) * 256;
    const int t0   = sp * KT;
    const int sw   = c16 & 7;

    // thread-fixed K-stage byte offsets (source pre-swizzled; dst linear, wave-uniform)
    int koff[4];
    #pragma unroll
    for (int j = 0; j < 4; ++j) {
        const int key  = wv * 16 + j * 4 + g;
        const int csrc = (c16 & 8) | ((c16 & 7) ^ (key & 7));
        koff[j] = (key * CCH + csrc * 8) * 2;
    }
    // stage K tile t into Kb[nb] (uniform t-dependent base + fixed per-lane offset)
    auto stageK = [&](int nb, int t) {
        const char* src = (const char*)F16 + (size_t)t * (KV * CCH * 2);
        #pragma unroll
        for (int j = 0; j < 4; ++j)
            __builtin_amdgcn_global_load_lds(
                (const __attribute__((address_space(1))) void*)(src + koff[j]),
                (__attribute__((address_space(3))) void*)(&Kb[nb][(wv * 16 + j * 4) * CCH]),
                16, 0, 0);
    };

    // thread-fixed V byte offsets
    int voff[8];
    #pragma unroll
    for (int kf = 0; kf < 2; ++kf)
        #pragma unroll
        for (int df = 0; df < 4; ++df)
            voff[kf * 4 + df] = (int)(((size_t)(d0 + wv * 64 + df * 16 + c16) * NS
                                       + kf * 32 + g * 8) * 2);

    // Q B-frags (col = query = n0 + wv*16 + c16, k = kk*32 + g*8 + e)
    f16x8 q[4];
    #pragma unroll
    for (int kk = 0; kk < 4; ++kk)
        q[kk] = *(const f16x8*)(F16 + (n0 + wv * 16 + c16) * CCH + kk * 32 + g * 8);

    f32x4 o[4][4];
    #pragma unroll
    for (int rf = 0; rf < 4; ++rf)
        #pragma unroll
        for (int df = 0; df < 4; ++df) o[rf][df] = 0.0f;
    float m_run = -20000.0f, l_run = 0.0f;   // m in log2 domain

    stageK(0, t0);
    __syncthreads();

    for (int tl = 0; tl < KT; ++tl) {
        const int buf = tl & 1;
        const int m0  = (t0 + tl) * KV;

        // ---- K stage for NEXT tile, issued FIRST (hides under QK+softmax) ----
        if (tl + 1 < KT) stageK(buf ^ 1, t0 + tl + 1);

        // ---- V prefetch for THIS tile (uniform base + fixed offsets -> saddr) ----
        const char* vt = (const char*)Vt + (size_t)m0 * 2;
        f16x8 vreg[8];
        #pragma unroll
        for (int i = 0; i < 8; ++i)
            vreg[i] = *(const f16x8*)(vt + voff[i]);

        // ---- QK^T (A = K from Kb, B = q): s[cf][r] -> key cf*16+g*4+r, query c16 ----
        f32x4 s[4];
        #pragma unroll
        for (int cf = 0; cf < 4; ++cf) s[cf] = 0.0f;
        __builtin_amdgcn_s_setprio(1);
        #pragma unroll
        for (int cf = 0; cf < 4; ++cf) {
            const _Float16* kr = &Kb[buf][(cf * 16 + c16) * CCH];
            #pragma unroll
            for (int kk = 0; kk < 4; ++kk) {
                const int c  = kk * 4 + g;
                const int cc = (c & 8) | ((c & 7) ^ sw);
                s[cf] = __builtin_amdgcn_mfma_f32_16x16x32_f16(
                            *(const f16x8*)(kr + cc * 8), q[kk], s[cf], 0, 0, 0);
            }
        }
        __builtin_amdgcn_s_setprio(0);

        const float* csvt = csv + m0;
        const float* csbt = csb + m0;
        f32x4 cs[4], cb[4];
        #pragma unroll
        for (int cf = 0; cf < 4; ++cf) {
            cs[cf] = *(const f32x4*)(csvt + cf * 16 + g * 4);
            cb[cf] = *(const f32x4*)(csbt + cf * 16 + g * 4);
        }

        // ---- softmax (log2 domain): sv = s*cs + cb (one fma; masked -> -60000) ----
        float tm = -1e30f;
        #pragma unroll
        for (int cf = 0; cf < 4; ++cf)
            #pragma unroll
            for (int r = 0; r < 4; ++r) {
                s[cf][r] = __builtin_fmaf(s[cf][r], cs[cf][r], cb[cf][r]);
                tm = fmaxf(tm, s[cf][r]);
            }
        tm = fmaxf(tm, __shfl_xor(tm, 16));
        tm = fmaxf(tm, __shfl_xor(tm, 32));

        float al = 1.0f;
        const bool trig = __any(tm > m_run + THR2);
        if (trig) {
            float nm = fmaxf(m_run, tm);
            al = EXP2(m_run - nm);
            l_run *= al; m_run = nm;
        }
        if (lane == 0) flags[buf][wv] = trig ? 1 : 0;
        if (g == 0)    abuf[buf][wv * 16 + c16] = al;

        // P = exp2(sv - m) (masked -> exactly 0), row-sum, swizzled b64 writes
        // (scalar _Float16 casts: compiler fuses to v_cvt_pkrtz — m240)
        float ps = 0.0f;
        const int prow = wv * 16 + c16;
        #pragma unroll
        for (int cf = 0; cf < 4; ++cf) {
            float e0 = EXP2(s[cf][0] - m_run);
            float e1 = EXP2(s[cf][1] - m_run);
            float e2 = EXP2(s[cf][2] - m_run);
            float e3 = EXP2(s[cf][3] - m_run);
            ps += (e0 + e1) + (e2 + e3);
            f16x4 ph = { (_Float16)e0, (_Float16)e1, (_Float16)e2, (_Float16)e3 };
            const int ch = (cf * 2 + (g >> 1)) ^ sw;
            *(f16x4*)(&Pb[buf][prow * KV + ch * 8 + (g & 1) * 4]) = ph;
        }
        ps += __shfl_xor(ps, 16);
        ps += __shfl_xor(ps, 32);
        l_run += ps;

        __syncthreads();   // the ONLY barrier: publishes P(t), abuf/flags(t), K(t+1)

        // ---- PV: O[64 rows][this wave's 64 d] from Pb[buf] + prefetched vreg ----
        {
            const int4 fl = *(const int4*)(&flags[buf][0]);
            if (fl.x | fl.y | fl.z | fl.w) {
                #pragma unroll
                for (int rf = 0; rf < 4; ++rf) {
                    f32x4 a4 = *(const f32x4*)(&abuf[buf][rf * 16 + g * 4]);
                    #pragma unroll
                    for (int df = 0; df < 4; ++df)
                        #pragma unroll
                        for (int r = 0; r < 4; ++r) o[rf][df][r] *= a4[r];
                }
            }
        }
        __builtin_amdgcn_s_setprio(1);
        #pragma unroll
        for (int kf = 0; kf < 2; ++kf) {
            f16x8 pa[4];
            #pragma unroll
            for (int rf = 0; rf < 4; ++rf)
                pa[rf] = *(const f16x8*)(&Pb[buf][(rf * 16 + c16) * KV
                                                  + (((kf * 4 + g) ^ sw) * 8)]);
            #pragma unroll
            for (int df = 0; df < 4; ++df)
                #pragma unroll
                for (int rf = 0; rf < 4; ++rf)
                    o[rf][df] = __builtin_amdgcn_mfma_f32_16x16x32_f16(
                                    pa[rf], vreg[kf * 4 + df], o[rf][df], 0, 0, 0);
        }
        __builtin_amdgcn_s_setprio(0);
    }

    // epilogue: share 1/l, write normalized partial O (f16) + logsumexp (e-domain)
    if (g == 0) {
        lbuf[wv * 16 + c16] = (l_run > 0.0f) ? 1.0f / l_run : 0.0f;
        if (d0 == 0)
            av[sp * NS + n0 + wv * 16 + c16] =
                (l_run > 0.0f) ? m_run * LN2 + __logf(l_run) : -1e30f;
    }
    __syncthreads();
    #pragma unroll
    for (int rf = 0; rf < 4; ++rf) {
        f32x4 li = *(const f32x4*)(&lbuf[rf * 16 + g * 4]);
        #pragma unroll
        for (int df = 0; df < 4; ++df) {
            f16x4 res;
            #pragma unroll
            for (int r = 0; r < 4; ++r) res[r] = (_Float16)(o[rf][df][r] * li[r]);
            *(f16x4*)(po + ((size_t)sp * DV + d0 + wv * 64 + df * 16 + c16) * NS
                          + n0 + rf * 16 + g * 4) = res;
        }
    }
}

// ---------- final: merge splits (logsumexp weights) + mask blend ----------
template<int S>
__global__ __launch_bounds__(192) void combine_kernel(const float* __restrict__ x,
        const float* __restrict__ mask, const _Float16* __restrict__ po,
        const float* __restrict__ av, float* __restrict__ out)
{
    int i = blockIdx.x;      // 0..95
    int c = blockIdx.y;      // 0..127
    int w = threadIdx.x;     // 0..191
    int n = i * 96 + (w >> 1);

    float A = -1e30f;
    #pragma unroll
    for (int s = 0; s < S; ++s) A = fmaxf(A, av[s * NS + n]);
    float wt[S], wsum = 0.0f;
    #pragma unroll
    for (int s = 0; s < S; ++s) {
        float a = av[s * NS + n];
        float e = (a > -1e29f) ? __expf(a - A) : 0.0f;
        wt[s] = e; wsum += e;
    }
    float invw = (wsum > 0.0f) ? 1.0f / wsum : 0.0f;

    #pragma unroll
    for (int di = 0; di < 2; ++di) {
        int h = 2 * i + di;
        int d = c * 4 + di * 2 + (w & 1);
        float rv = 0.0f;
        #pragma unroll
        for (int s = 0; s < S; ++s)
            rv += wt[s] * (float)po[((size_t)s * DV + d) * NS + n];
        rv *= invw;
        float xv = x[c * HW + h * W_ + w];
        float mv = mask[h * W_ + w];
        out[c * HW + h * W_ + w] = xv * (1.0f - mv) + rv * mv;
    }
}

extern "C" void kernel_launch(void* const* d_in, const int* in_sizes, int n_in,
                              void* d_out, int out_size, void* d_ws, size_t ws_size,
                              hipStream_t stream) {
    const float* x    = (const float*)d_in[0];
    const float* mask = (const float*)d_in[1];
    float* out = (float*)d_out;

    char* ws = (char*)d_ws;
    _Float16* Vt  = (_Float16*)(ws);                     //  9,437,184 B
    _Float16* F16 = (_Float16*)(ws + 9437184);           //  2,359,296 B
    float*    csv = (float*)   (ws + 11796480);          //     36,864 B
    float*    csb = (float*)   (ws + 11833344);          //     36,864 B
    float*    av  = (float*)   (ws + 11870208);          //    294,912 B
    _Float16* po  = (_Float16*)(ws + 12165120);          //  SPL * 9,437,184 B

    prep_vt_kernel <<<dim3(36, 512), 256, 0, stream>>>(x, Vt, F16);
    prep_csv_kernel<<<NS, 64, 0, stream>>>(F16, mask, csv, csb);

    const size_t base = 12165120ull;
    if (ws_size >= base + 8ull * 9437184ull) {
        flash_kernel<18><<<288 * 8, 256, 0, stream>>>(F16, Vt, csv, csb, po, av);
        combine_kernel<8><<<dim3(96, 128), 192, 0, stream>>>(x, mask, po, av, out);
    } else {
        flash_kernel<36><<<288 * 4, 256, 0, stream>>>(F16, Vt, csv, csb, po, av);
        combine_kernel<4><<<dim3(96, 128), 192, 0, stream>>>(x, mask, po, av, out);
    }
}

// Round 10
// 462.878 us; speedup vs baseline: 1.1414x; 1.1414x over previous
//
#include <hip/hip_runtime.h>
#include <hip/hip_bf16.h>

typedef _Float16 f16x8 __attribute__((ext_vector_type(8)));
typedef _Float16 f16x4 __attribute__((ext_vector_type(4)));
typedef float    f32x4 __attribute__((ext_vector_type(4)));

#define HW   36864   // 192*192
#define W_   192
#define NS   9216    // 96*96 patches
#define CCH  128     // channels (QK inner dim)
#define DV   512     // c*r*r  (PV output dim)
#define ROWS 64      // query rows per block
#define KV   32      // keys per tile
#define NT2  288     // total 32-key tiles
#define LOG2E 1.44269504089f
#define LN2   0.69314718056f
#define THR2  11.5417f        // defer-max threshold (=8 nats) in log2 domain
#define EXP2(x) __builtin_exp2f(x)

// ---------- prep: Vt[d][m] (f16, transposed patches) + F16[m][c] (f16 feat) ----------
__global__ __launch_bounds__(256) void prep_vt_kernel(const float* __restrict__ x,
        _Float16* __restrict__ Vt, _Float16* __restrict__ F16)
{
    int m = blockIdx.x * 256 + threadIdx.x;   // 0..9215
    int d = blockIdx.y;                       // 0..511
    int c = d >> 2, di = (d >> 1) & 1, dj = d & 1;
    int i = m / 96, j = m - i * 96;
    float v = x[c * HW + (2 * i + di) * W_ + (2 * j + dj)];
    _Float16 h = (_Float16)v;
    Vt[(size_t)d * NS + m] = h;
    if ((d & 3) == 0) F16[m * CCH + c] = h;   // di=dj=0 element == feat
}

// ---------- prep: csv[m] = valid ? 10*log2e/(||f||+eps) : 0 ----------
__global__ __launch_bounds__(64) void prep_csv_kernel(const _Float16* __restrict__ F16,
        const float* __restrict__ mask, float* __restrict__ csv)
{
    int m = blockIdx.x;
    int t = threadIdx.x;                      // one wave
    float a = (float)F16[m * CCH + 2 * t];
    float b = (float)F16[m * CCH + 2 * t + 1];
    float ss = a * a + b * b;
    #pragma unroll
    for (int off = 1; off <= 32; off <<= 1)
        ss += __shfl_xor(ss, off);
    if (t == 0) {
        int i = m / 96, j = m - i * 96;
        float ms = mask[(2 * i) * W_ + 2 * j];
        csv[m] = (ms == 0.0f) ? 10.0f * LOG2E / (sqrtf(ss) + 1e-8f) : 0.0f;
    }
}

// ---------- fused masked attention: 64 rows x 256 d, 4 waves, KV=32, 1 barrier/tile ----
// r7 structure (proven): V prefetch at top, QK, softmax (log2 domain), P-write,
// stageK(t+1) just before the single barrier, then PV. Smaller KV for 4 waves/SIMD.
template<int KT>
__global__ __launch_bounds__(256, 4) void flash_kernel(const _Float16* __restrict__ F16,
        const _Float16* __restrict__ Vt, const float* __restrict__ csv,
        _Float16* __restrict__ po, float* __restrict__ av)
{
    constexpr int SPLT = NT2 / KT;
    __shared__ __align__(16) _Float16 Kb[2][KV * CCH];   // 2 x 8 KB, [key][chunk^(key&7)]
    __shared__ __align__(16) _Float16 Pb[2][ROWS * KV];  // 2 x 4 KB, [row][chunk^(row&3)]
    __shared__ __align__(16) float    abuf[2][ROWS];     // per-row rescale factors
    __shared__ __align__(16) int      flags[2][4];       // per-wave rescale flags
    __shared__ __align__(16) float    lbuf[ROWS];        // final 1/l

    const int tid  = threadIdx.x;
    const int wv   = tid >> 6;
    const int lane = tid & 63;
    const int g    = lane >> 4, c16 = lane & 15;
    const int flat = blockIdx.x;
    const int sp   = flat % SPLT;      // same split -> same XCD (round-robin dispatch)
    const int rest = flat / SPLT;
    const int n0   = (rest >> 1) * ROWS;
    const int d0   = (rest & 1) * 256;
    const int t0   = sp * KT;
    const int sw   = c16 & 7;

    // stage K tile t into Kb[nb]: wave covers keys wv*8..+7, pre-swizzled global src
    auto stageK = [&](int nb, int t) {
        #pragma unroll
        for (int j = 0; j < 2; ++j) {
            const int key  = wv * 8 + j * 4 + g;
            const int csrc = (c16 & 8) | ((c16 & 7) ^ (key & 7));
            __builtin_amdgcn_global_load_lds(
                (const __attribute__((address_space(1))) void*)
                    (F16 + (size_t)(t * KV + key) * CCH + csrc * 8),
                (__attribute__((address_space(3))) void*)
                    (&Kb[nb][(wv * 8 + j * 4) * CCH]),
                16, 0, 0);
        }
    };

    // Q B-frags (col = query = n0 + wv*16 + c16, k = kk*32 + g*8 + e)
    f16x8 q[4];
    #pragma unroll
    for (int kk = 0; kk < 4; ++kk)
        q[kk] = *(const f16x8*)(F16 + (n0 + wv * 16 + c16) * CCH + kk * 32 + g * 8);

    f32x4 o[4][4];
    #pragma unroll
    for (int rf = 0; rf < 4; ++rf)
        #pragma unroll
        for (int df = 0; df < 4; ++df) o[rf][df] = 0.0f;
    float m_run = -20000.0f, l_run = 0.0f;   // m in log2 domain

    const _Float16* vbase = Vt + (size_t)(d0 + wv * 64 + c16) * NS + g * 8;

    stageK(0, t0);
    __syncthreads();

    for (int tl = 0; tl < KT; ++tl) {
        const int buf = tl & 1;
        const int m0  = (t0 + tl) * KV;

        // ---- V prefetch for THIS tile (consumed in PV after the barrier) ----
        f16x8 vreg[4];
        #pragma unroll
        for (int df = 0; df < 4; ++df)
            vreg[df] = *(const f16x8*)(vbase + (size_t)(df * 16) * NS + m0);

        // ---- QK^T (A = K from Kb, B = q): s[cf][r] -> key cf*16+g*4+r, query c16 ----
        f32x4 s[2];
        s[0] = 0.0f; s[1] = 0.0f;
        __builtin_amdgcn_s_setprio(1);
        #pragma unroll
        for (int cf = 0; cf < 2; ++cf) {
            const _Float16* kr = &Kb[buf][(cf * 16 + c16) * CCH];
            #pragma unroll
            for (int kk = 0; kk < 4; ++kk) {
                const int c  = kk * 4 + g;
                const int cc = (c & 8) | ((c & 7) ^ sw);
                s[cf] = __builtin_amdgcn_mfma_f32_16x16x32_f16(
                            *(const f16x8*)(kr + cc * 8), q[kk], s[cf], 0, 0, 0);
            }
        }
        __builtin_amdgcn_s_setprio(0);

        f32x4 cs[2];
        cs[0] = *(const f32x4*)(csv + m0 + g * 4);
        cs[1] = *(const f32x4*)(csv + m0 + 16 + g * 4);

        // ---- softmax (log2 domain): sv = cs>0 ? s*cs : -60000 (masked) ----
        float tm = -1e30f;
        #pragma unroll
        for (int cf = 0; cf < 2; ++cf)
            #pragma unroll
            for (int r = 0; r < 4; ++r) {
                float v = (cs[cf][r] > 0.0f) ? s[cf][r] * cs[cf][r] : -60000.0f;
                s[cf][r] = v;
                tm = fmaxf(tm, v);
            }
        tm = fmaxf(tm, __shfl_xor(tm, 16));
        tm = fmaxf(tm, __shfl_xor(tm, 32));

        float al = 1.0f;
        const bool trig = __any(tm > m_run + THR2);
        if (trig) {
            float nm = fmaxf(m_run, tm);
            al = EXP2(m_run - nm);
            l_run *= al; m_run = nm;
        }
        if (lane == 0) flags[buf][wv] = trig ? 1 : 0;
        if (g == 0)    abuf[buf][wv * 16 + c16] = al;

        // P = exp2(sv - m) (masked -> exactly 0), row-sum, swizzled b64 writes
        float ps = 0.0f;
        const int prow = wv * 16 + c16;
        #pragma unroll
        for (int cf = 0; cf < 2; ++cf) {
            float e0 = EXP2(s[cf][0] - m_run);
            float e1 = EXP2(s[cf][1] - m_run);
            float e2 = EXP2(s[cf][2] - m_run);
            float e3 = EXP2(s[cf][3] - m_run);
            ps += (e0 + e1) + (e2 + e3);
            f16x4 ph = { (_Float16)e0, (_Float16)e1, (_Float16)e2, (_Float16)e3 };
            const int ch = (cf * 2 + (g >> 1)) ^ (c16 & 3);
            *(f16x4*)(&Pb[buf][prow * KV + ch * 8 + (g & 1) * 4]) = ph;
        }
        ps += __shfl_xor(ps, 16);
        ps += __shfl_xor(ps, 32);
        l_run += ps;

        // async K stage for next tile (arrives by the barrier's implicit vmcnt drain)
        if (tl + 1 < KT) stageK(buf ^ 1, t0 + tl + 1);

        __syncthreads();   // the ONLY barrier: publishes P(t), abuf/flags(t), K(t+1)

        // ---- PV: O[64 rows][this wave's 64 d] from Pb[buf] + prefetched vreg ----
        {
            const int4 fl = *(const int4*)(&flags[buf][0]);
            if (fl.x | fl.y | fl.z | fl.w) {
                #pragma unroll
                for (int rf = 0; rf < 4; ++rf) {
                    f32x4 a4 = *(const f32x4*)(&abuf[buf][rf * 16 + g * 4]);
                    #pragma unroll
                    for (int df = 0; df < 4; ++df)
                        #pragma unroll
                        for (int r = 0; r < 4; ++r) o[rf][df][r] *= a4[r];
                }
            }
        }
        __builtin_amdgcn_s_setprio(1);
        {
            f16x8 pa[4];
            #pragma unroll
            for (int rf = 0; rf < 4; ++rf)
                pa[rf] = *(const f16x8*)(&Pb[buf][(rf * 16 + c16) * KV
                                                  + ((g ^ (c16 & 3)) * 8)]);
            #pragma unroll
            for (int df = 0; df < 4; ++df)
                #pragma unroll
                for (int rf = 0; rf < 4; ++rf)
                    o[rf][df] = __builtin_amdgcn_mfma_f32_16x16x32_f16(
                                    pa[rf], vreg[df], o[rf][df], 0, 0, 0);
        }
        __builtin_amdgcn_s_setprio(0);
    }

    // epilogue: share 1/l, write normalized partial O (f16) + logsumexp (e-domain)
    if (g == 0) {
        lbuf[wv * 16 + c16] = (l_run > 0.0f) ? 1.0f / l_run : 0.0f;
        if (d0 == 0)
            av[sp * NS + n0 + wv * 16 + c16] =
                (l_run > 0.0f) ? m_run * LN2 + __logf(l_run) : -1e30f;
    }
    __syncthreads();
    #pragma unroll
    for (int rf = 0; rf < 4; ++rf) {
        f32x4 li = *(const f32x4*)(&lbuf[rf * 16 + g * 4]);
        #pragma unroll
        for (int df = 0; df < 4; ++df) {
            f16x4 res;
            #pragma unroll
            for (int r = 0; r < 4; ++r) res[r] = (_Float16)(o[rf][df][r] * li[r]);
            *(f16x4*)(po + ((size_t)sp * DV + d0 + wv * 64 + df * 16 + c16) * NS
                          + n0 + rf * 16 + g * 4) = res;
        }
    }
}

// ---------- final: merge splits (logsumexp weights) + mask blend ----------
template<int S>
__global__ __launch_bounds__(192) void combine_kernel(const float* __restrict__ x,
        const float* __restrict__ mask, const _Float16* __restrict__ po,
        const float* __restrict__ av, float* __restrict__ out)
{
    int i = blockIdx.x;      // 0..95
    int c = blockIdx.y;      // 0..127
    int w = threadIdx.x;     // 0..191
    int n = i * 96 + (w >> 1);

    float A = -1e30f;
    #pragma unroll
    for (int s = 0; s < S; ++s) A = fmaxf(A, av[s * NS + n]);
    float wt[S], wsum = 0.0f;
    #pragma unroll
    for (int s = 0; s < S; ++s) {
        float a = av[s * NS + n];
        float e = (a > -1e29f) ? __expf(a - A) : 0.0f;
        wt[s] = e; wsum += e;
    }
    float invw = (wsum > 0.0f) ? 1.0f / wsum : 0.0f;

    #pragma unroll
    for (int di = 0; di < 2; ++di) {
        int h = 2 * i + di;
        int d = c * 4 + di * 2 + (w & 1);
        float rv = 0.0f;
        #pragma unroll
        for (int s = 0; s < S; ++s)
            rv += wt[s] * (float)po[((size_t)s * DV + d) * NS + n];
        rv *= invw;
        float xv = x[c * HW + h * W_ + w];
        float mv = mask[h * W_ + w];
        out[c * HW + h * W_ + w] = xv * (1.0f - mv) + rv * mv;
    }
}

extern "C" void kernel_launch(void* const* d_in, const int* in_sizes, int n_in,
                              void* d_out, int out_size, void* d_ws, size_t ws_size,
                              hipStream_t stream) {
    const float* x    = (const float*)d_in[0];
    const float* mask = (const float*)d_in[1];
    float* out = (float*)d_out;

    char* ws = (char*)d_ws;
    _Float16* Vt  = (_Float16*)(ws);                     //  9,437,184 B
    _Float16* F16 = (_Float16*)(ws + 9437184);           //  2,359,296 B
    float*    csv = (float*)   (ws + 11796480);          //     36,864 B
    float*    av  = (float*)   (ws + 11833344);          //    294,912 B
    _Float16* po  = (_Float16*)(ws + 12128256);          //  SPL * 9,437,184 B

    prep_vt_kernel <<<dim3(36, 512), 256, 0, stream>>>(x, Vt, F16);
    prep_csv_kernel<<<NS, 64, 0, stream>>>(F16, mask, csv);

    const size_t base = 12128256ull;
    if (ws_size >= base + 8ull * 9437184ull) {
        flash_kernel<36><<<288 * 8, 256, 0, stream>>>(F16, Vt, csv, po, av);
        combine_kernel<8><<<dim3(96, 128), 192, 0, stream>>>(x, mask, po, av, out);
    } else {
        flash_kernel<72><<<288 * 4, 256, 0, stream>>>(F16, Vt, csv, po, av);
        combine_kernel<4><<<dim3(96, 128), 192, 0, stream>>>(x, mask, po, av, out);
    }
}

// Round 11
// 378.952 us; speedup vs baseline: 1.3942x; 1.2215x over previous
//
#include <hip/hip_runtime.h>
#include <hip/hip_bf16.h>

typedef _Float16 f16x8 __attribute__((ext_vector_type(8)));
typedef _Float16 f16x4 __attribute__((ext_vector_type(4)));
typedef float    f32x4 __attribute__((ext_vector_type(4)));

#define HW   36864   // 192*192
#define W_   192
#define NS   9216    // 96*96 patches
#define CCH  128     // channels (QK inner dim)
#define DV   512     // c*r*r  (PV output dim)
#define ROWS 64      // query rows per block
#define KV   64      // keys per tile
#define NT   144     // total key tiles
#define LOG2E 1.44269504089f
#define LN2   0.69314718056f
#define THR2  11.5417f        // defer-max threshold (=8 nats) in log2 domain
#define EXP2(x) __builtin_exp2f(x)

// ---------- prep: Vt[d][m] (f16, transposed patches) + F16[m][c] (f16 feat) ----------
__global__ __launch_bounds__(256) void prep_vt_kernel(const float* __restrict__ x,
        _Float16* __restrict__ Vt, _Float16* __restrict__ F16)
{
    int m = blockIdx.x * 256 + threadIdx.x;   // 0..9215
    int d = blockIdx.y;                       // 0..511
    int c = d >> 2, di = (d >> 1) & 1, dj = d & 1;
    int i = m / 96, j = m - i * 96;
    float v = x[c * HW + (2 * i + di) * W_ + (2 * j + dj)];
    _Float16 h = (_Float16)v;
    Vt[(size_t)d * NS + m] = h;
    if ((d & 3) == 0) F16[m * CCH + c] = h;   // di=dj=0 element == feat
}

// ---------- prep: csv[m] = valid ? 10*log2e/(||f||+eps) : 0 ----------
__global__ __launch_bounds__(64) void prep_csv_kernel(const _Float16* __restrict__ F16,
        const float* __restrict__ mask, float* __restrict__ csv)
{
    int m = blockIdx.x;
    int t = threadIdx.x;                      // one wave
    float a = (float)F16[m * CCH + 2 * t];
    float b = (float)F16[m * CCH + 2 * t + 1];
    float ss = a * a + b * b;
    #pragma unroll
    for (int off = 1; off <= 32; off <<= 1)
        ss += __shfl_xor(ss, off);
    if (t == 0) {
        int i = m / 96, j = m - i * 96;
        float ms = mask[(2 * i) * W_ + 2 * j];
        csv[m] = (ms == 0.0f) ? 10.0f * LOG2E / (sqrtf(ss) + 1e-8f) : 0.0f;
    }
}

// ---------- fused masked attention: 64 rows x 256 d, 4 waves, pipelined PV ----------
// r7 skeleton; body of iter tl: rescale(tl-1) -> PV(tl-1) INTERLEAVED with QK(tl)
// (two independent MFMA chains fill the matrix pipe) -> V(tl) -> softmax(tl) ->
// P-write(tl) -> stageK(tl+1) -> single barrier.
template<int KT>
__global__ __launch_bounds__(256, 3) void flash_kernel(const _Float16* __restrict__ F16,
        const _Float16* __restrict__ Vt, const float* __restrict__ csv,
        _Float16* __restrict__ po, float* __restrict__ av)
{
    constexpr int SPLT = NT / KT;
    __shared__ __align__(16) _Float16 Kb[2][KV * CCH];   // 2 x 16 KB, [key][chunk^(key&7)]
    __shared__ __align__(16) _Float16 Pb[2][ROWS * KV];  // 2 x 8 KB,  [row][chunk^(row&7)]
    __shared__ __align__(16) float    abuf[2][ROWS];     // per-row rescale factors
    __shared__ __align__(16) int      flags[2][4];       // per-wave rescale flags
    __shared__ __align__(16) float    lbuf[ROWS];        // final 1/l

    const int tid  = threadIdx.x;
    const int wv   = tid >> 6;
    const int lane = tid & 63;
    const int g    = lane >> 4, c16 = lane & 15;
    const int flat = blockIdx.x;
    const int sp   = flat % SPLT;      // same split -> same XCD (round-robin dispatch)
    const int rest = flat / SPLT;
    const int n0   = (rest >> 1) * ROWS;
    const int d0   = (rest & 1) * 256;
    const int t0   = sp * KT;
    const int sw   = c16 & 7;

    // stage K tile t into Kb[nb]: wave covers keys wv*16..+15, pre-swizzled global src
    auto stageK = [&](int nb, int t) {
        #pragma unroll
        for (int j = 0; j < 4; ++j) {
            const int key  = wv * 16 + j * 4 + g;
            const int csrc = (c16 & 8) | ((c16 & 7) ^ (key & 7));
            __builtin_amdgcn_global_load_lds(
                (const __attribute__((address_space(1))) void*)
                    (F16 + (size_t)(t * KV + key) * CCH + csrc * 8),
                (__attribute__((address_space(3))) void*)
                    (&Kb[nb][(wv * 16 + j * 4) * CCH]),
                16, 0, 0);
        }
    };

    // Q B-frags (col = query = n0 + wv*16 + c16, k = kk*32 + g*8 + e)
    f16x8 q[4];
    #pragma unroll
    for (int kk = 0; kk < 4; ++kk)
        q[kk] = *(const f16x8*)(F16 + (n0 + wv * 16 + c16) * CCH + kk * 32 + g * 8);

    f32x4 o[4][4];
    #pragma unroll
    for (int rf = 0; rf < 4; ++rf)
        #pragma unroll
        for (int df = 0; df < 4; ++df) o[rf][df] = 0.0f;
    float m_run = -20000.0f, l_run = 0.0f;   // m in log2 domain

    const _Float16* vbase = Vt + (size_t)(d0 + wv * 64 + c16) * NS + g * 8;
    f16x8 vreg[8];

    stageK(0, t0);
    __syncthreads();

    // softmax + P-write for tile tl (s already holds raw QK result)
    auto softmax_store = [&](int kb, int m0, f32x4* s) {
        f32x4 cs[4];
        #pragma unroll
        for (int cf = 0; cf < 4; ++cf)
            cs[cf] = *(const f32x4*)(csv + m0 + cf * 16 + g * 4);
        float tm = -1e30f;
        #pragma unroll
        for (int cf = 0; cf < 4; ++cf)
            #pragma unroll
            for (int r = 0; r < 4; ++r) {
                float v = (cs[cf][r] > 0.0f) ? s[cf][r] * cs[cf][r] : -60000.0f;
                s[cf][r] = v;
                tm = fmaxf(tm, v);
            }
        tm = fmaxf(tm, __shfl_xor(tm, 16));
        tm = fmaxf(tm, __shfl_xor(tm, 32));
        float al = 1.0f;
        const bool trig = __any(tm > m_run + THR2);
        if (trig) {
            float nm = fmaxf(m_run, tm);
            al = EXP2(m_run - nm);
            l_run *= al; m_run = nm;
        }
        if (lane == 0) flags[kb][wv] = trig ? 1 : 0;
        if (g == 0)    abuf[kb][wv * 16 + c16] = al;
        float ps = 0.0f;
        const int prow = wv * 16 + c16;
        #pragma unroll
        for (int cf = 0; cf < 4; ++cf) {
            float e0 = EXP2(s[cf][0] - m_run);
            float e1 = EXP2(s[cf][1] - m_run);
            float e2 = EXP2(s[cf][2] - m_run);
            float e3 = EXP2(s[cf][3] - m_run);
            ps += (e0 + e1) + (e2 + e3);
            f16x4 ph = { (_Float16)e0, (_Float16)e1, (_Float16)e2, (_Float16)e3 };
            const int ch = (cf * 2 + (g >> 1)) ^ sw;
            *(f16x4*)(&Pb[kb][prow * KV + ch * 8 + (g & 1) * 4]) = ph;
        }
        ps += __shfl_xor(ps, 16);
        ps += __shfl_xor(ps, 32);
        l_run += ps;
    };

    // rescale accumulator from abuf[pb] (if any wave triggered)
    auto rescale = [&](int pb) {
        const int4 fl = *(const int4*)(&flags[pb][0]);
        if (fl.x | fl.y | fl.z | fl.w) {
            #pragma unroll
            for (int rf = 0; rf < 4; ++rf) {
                f32x4 a4 = *(const f32x4*)(&abuf[pb][rf * 16 + g * 4]);
                #pragma unroll
                for (int df = 0; df < 4; ++df)
                    #pragma unroll
                    for (int r = 0; r < 4; ++r) o[rf][df][r] *= a4[r];
            }
        }
    };

    // ---- peeled iteration 0: QK(0)+softmax(0)+P-write(0), V(0) prefetch, no PV ----
    {
        const int m0 = t0 * KV;
        #pragma unroll
        for (int i = 0; i < 8; ++i)
            vreg[i] = *(const f16x8*)(vbase + (size_t)((i & 3) * 16) * NS + m0 + (i >> 2) * 32);
        f32x4 s[4];
        #pragma unroll
        for (int cf = 0; cf < 4; ++cf) s[cf] = 0.0f;
        __builtin_amdgcn_s_setprio(1);
        #pragma unroll
        for (int cf = 0; cf < 4; ++cf) {
            const _Float16* kr = &Kb[0][(cf * 16 + c16) * CCH];
            #pragma unroll
            for (int kk = 0; kk < 4; ++kk) {
                const int c  = kk * 4 + g;
                const int cc = (c & 8) | ((c & 7) ^ sw);
                s[cf] = __builtin_amdgcn_mfma_f32_16x16x32_f16(
                            *(const f16x8*)(kr + cc * 8), q[kk], s[cf], 0, 0, 0);
            }
        }
        __builtin_amdgcn_s_setprio(0);
        softmax_store(0, m0, s);
        if (KT > 1) stageK(1, t0 + 1);
        __syncthreads();
    }

    // ---- main loop: body tl does PV(tl-1) interleaved with QK(tl) ----
    for (int tl = 1; tl < KT; ++tl) {
        const int pb = (tl - 1) & 1;
        const int kb = tl & 1;
        const int m0 = (t0 + tl) * KV;

        rescale(pb);

        f32x4 s[4];
        #pragma unroll
        for (int cf = 0; cf < 4; ++cf) s[cf] = 0.0f;

        __builtin_amdgcn_s_setprio(1);
        // PV(tl-1) kf=0 reads + QK(tl) cf=0,1 + PV kf=0 MFMAs (independent chains mix)
        {
            f16x8 pa[4];
            #pragma unroll
            for (int rf = 0; rf < 4; ++rf)
                pa[rf] = *(const f16x8*)(&Pb[pb][(rf * 16 + c16) * KV + ((g ^ sw) * 8)]);
            #pragma unroll
            for (int cf = 0; cf < 2; ++cf) {
                const _Float16* kr = &Kb[kb][(cf * 16 + c16) * CCH];
                #pragma unroll
                for (int kk = 0; kk < 4; ++kk) {
                    const int c  = kk * 4 + g;
                    const int cc = (c & 8) | ((c & 7) ^ sw);
                    s[cf] = __builtin_amdgcn_mfma_f32_16x16x32_f16(
                                *(const f16x8*)(kr + cc * 8), q[kk], s[cf], 0, 0, 0);
                }
            }
            #pragma unroll
            for (int df = 0; df < 4; ++df)
                #pragma unroll
                for (int rf = 0; rf < 4; ++rf)
                    o[rf][df] = __builtin_amdgcn_mfma_f32_16x16x32_f16(
                                    pa[rf], vreg[df], o[rf][df], 0, 0, 0);
        }
        // PV(tl-1) kf=1 reads + QK(tl) cf=2,3 + PV kf=1 MFMAs
        {
            f16x8 pa[4];
            #pragma unroll
            for (int rf = 0; rf < 4; ++rf)
                pa[rf] = *(const f16x8*)(&Pb[pb][(rf * 16 + c16) * KV + (((4 + g) ^ sw) * 8)]);
            #pragma unroll
            for (int cf = 2; cf < 4; ++cf) {
                const _Float16* kr = &Kb[kb][(cf * 16 + c16) * CCH];
                #pragma unroll
                for (int kk = 0; kk < 4; ++kk) {
                    const int c  = kk * 4 + g;
                    const int cc = (c & 8) | ((c & 7) ^ sw);
                    s[cf] = __builtin_amdgcn_mfma_f32_16x16x32_f16(
                                *(const f16x8*)(kr + cc * 8), q[kk], s[cf], 0, 0, 0);
                }
            }
            #pragma unroll
            for (int df = 0; df < 4; ++df)
                #pragma unroll
                for (int rf = 0; rf < 4; ++rf)
                    o[rf][df] = __builtin_amdgcn_mfma_f32_16x16x32_f16(
                                    pa[rf], vreg[4 + df], o[rf][df], 0, 0, 0);
        }
        __builtin_amdgcn_s_setprio(0);

        // V(tl) loads (vreg now free; consumed next body — latency spans softmax+barrier)
        #pragma unroll
        for (int i = 0; i < 8; ++i)
            vreg[i] = *(const f16x8*)(vbase + (size_t)((i & 3) * 16) * NS + m0 + (i >> 2) * 32);

        softmax_store(kb, m0, s);

        if (tl + 1 < KT) stageK((tl + 1) & 1, t0 + tl + 1);

        __syncthreads();   // publishes P(tl), abuf/flags(tl), K(tl+1)
    }

    // ---- final PV(KT-1) ----
    {
        const int pb = (KT - 1) & 1;
        rescale(pb);
        __builtin_amdgcn_s_setprio(1);
        #pragma unroll
        for (int kf = 0; kf < 2; ++kf) {
            f16x8 pa[4];
            #pragma unroll
            for (int rf = 0; rf < 4; ++rf)
                pa[rf] = *(const f16x8*)(&Pb[pb][(rf * 16 + c16) * KV
                                                  + (((kf * 4 + g) ^ sw) * 8)]);
            #pragma unroll
            for (int df = 0; df < 4; ++df)
                #pragma unroll
                for (int rf = 0; rf < 4; ++rf)
                    o[rf][df] = __builtin_amdgcn_mfma_f32_16x16x32_f16(
                                    pa[rf], vreg[kf * 4 + df], o[rf][df], 0, 0, 0);
        }
        __builtin_amdgcn_s_setprio(0);
    }

    // epilogue: share 1/l, write normalized partial O (f16) + logsumexp (e-domain)
    if (g == 0) {
        lbuf[wv * 16 + c16] = (l_run > 0.0f) ? 1.0f / l_run : 0.0f;
        if (d0 == 0)
            av[sp * NS + n0 + wv * 16 + c16] =
                (l_run > 0.0f) ? m_run * LN2 + __logf(l_run) : -1e30f;
    }
    __syncthreads();
    #pragma unroll
    for (int rf = 0; rf < 4; ++rf) {
        f32x4 li = *(const f32x4*)(&lbuf[rf * 16 + g * 4]);
        #pragma unroll
        for (int df = 0; df < 4; ++df) {
            f16x4 res;
            #pragma unroll
            for (int r = 0; r < 4; ++r) res[r] = (_Float16)(o[rf][df][r] * li[r]);
            *(f16x4*)(po + ((size_t)sp * DV + d0 + wv * 64 + df * 16 + c16) * NS
                          + n0 + rf * 16 + g * 4) = res;
        }
    }
}

// ---------- final: merge splits (logsumexp weights) + mask blend ----------
template<int S>
__global__ __launch_bounds__(192) void combine_kernel(const float* __restrict__ x,
        const float* __restrict__ mask, const _Float16* __restrict__ po,
        const float* __restrict__ av, float* __restrict__ out)
{
    int i = blockIdx.x;      // 0..95
    int c = blockIdx.y;      // 0..127
    int w = threadIdx.x;     // 0..191
    int n = i * 96 + (w >> 1);

    float A = -1e30f;
    #pragma unroll
    for (int s = 0; s < S; ++s) A = fmaxf(A, av[s * NS + n]);
    float wt[S], wsum = 0.0f;
    #pragma unroll
    for (int s = 0; s < S; ++s) {
        float a = av[s * NS + n];
        float e = (a > -1e29f) ? __expf(a - A) : 0.0f;
        wt[s] = e; wsum += e;
    }
    float invw = (wsum > 0.0f) ? 1.0f / wsum : 0.0f;

    #pragma unroll
    for (int di = 0; di < 2; ++di) {
        int h = 2 * i + di;
        int d = c * 4 + di * 2 + (w & 1);
        float rv = 0.0f;
        #pragma unroll
        for (int s = 0; s < S; ++s)
            rv += wt[s] * (float)po[((size_t)s * DV + d) * NS + n];
        rv *= invw;
        float xv = x[c * HW + h * W_ + w];
        float mv = mask[h * W_ + w];
        out[c * HW + h * W_ + w] = xv * (1.0f - mv) + rv * mv;
    }
}

extern "C" void kernel_launch(void* const* d_in, const int* in_sizes, int n_in,
                              void* d_out, int out_size, void* d_ws, size_t ws_size,
                              hipStream_t stream) {
    const float* x    = (const float*)d_in[0];
    const float* mask = (const float*)d_in[1];
    float* out = (float*)d_out;

    char* ws = (char*)d_ws;
    _Float16* Vt  = (_Float16*)(ws);                     //  9,437,184 B
    _Float16* F16 = (_Float16*)(ws + 9437184);           //  2,359,296 B
    float*    csv = (float*)   (ws + 11796480);          //     36,864 B
    float*    av  = (float*)   (ws + 11833344);          //    294,912 B
    _Float16* po  = (_Float16*)(ws + 12128256);          //  SPL * 9,437,184 B

    prep_vt_kernel <<<dim3(36, 512), 256, 0, stream>>>(x, Vt, F16);
    prep_csv_kernel<<<NS, 64, 0, stream>>>(F16, mask, csv);

    const size_t base = 12128256ull;
    if (ws_size >= base + 8ull * 9437184ull) {
        flash_kernel<18><<<288 * 8, 256, 0, stream>>>(F16, Vt, csv, po, av);
        combine_kernel<8><<<dim3(96, 128), 192, 0, stream>>>(x, mask, po, av, out);
    } else {
        flash_kernel<36><<<288 * 4, 256, 0, stream>>>(F16, Vt, csv, po, av);
        combine_kernel<4><<<dim3(96, 128), 192, 0, stream>>>(x, mask, po, av, out);
    }
}